// Round 4
// baseline (150.494 us; speedup 1.0000x reference)
//
#include <hip/hip_runtime.h>
#include <math.h>

#define NC 17
#define PLANE 640000            // 200*200*16
#define NVOX (2 * PLANE)        // 1,280,000 voxels  (= 5000 * 256 exactly)
#define NBLK (NVOX / 256)       // 5000 blocks, 1 voxel/thread
#define SLOT 16                 // floats per accumulator slot (64 B -> own L2 line)
#define BETA_C 0.95f
#define ALPHA_C 5.0f
#define WPC_C 3.0f
#define IGNORE_C 255

// acc layout (padded): nom[c] at acc[c*SLOT], sum_p[c] at acc[(NC+c)*SLOT],
// sum_comp[c] at acc[(2*NC+c)*SLOT]. 51 slots * 64 B = 3264 B of d_ws.

// ---------------------------------------------------------------------------
// Kernel 1: per-voxel softmax + per-class sums. 1 voxel/thread, max TLP.
// ---------------------------------------------------------------------------
__global__ __launch_bounds__(256) void al_reduce(const float* __restrict__ pred,
                                                 const int* __restrict__ tgt,
                                                 float* __restrict__ acc) {
    const int v = blockIdx.x * 256 + (int)threadIdx.x;   // exact, no loop
    const int b = (v >= PLANE) ? 1 : 0;
    const int n = v - b * PLANE;
    const float* p0 = pred + (size_t)(b * NC) * PLANE + n;
    const int t = tgt[v];

    // 17 independent coalesced loads (256 B/wave each), all in flight
    float x[NC];
#pragma unroll
    for (int c = 0; c < NC; ++c) x[c] = p0[(size_t)c * PLANE];

    float mx = x[0];
#pragma unroll
    for (int c = 1; c < NC; ++c) mx = fmaxf(mx, x[c]);

    float s = 0.f;
#pragma unroll
    for (int c = 0; c < NC; ++c) { x[c] = __expf(x[c] - mx); s += x[c]; }

    // fold ignore-mask into the reciprocal
    const float iw = (t != IGNORE_C) ? (1.0f / s) : 0.0f;

    __shared__ float lds[3 * NC];   // [0..16]=nom, [17..33]=sum_p, [34..50]=cnt
    if (threadIdx.x < 3 * NC) lds[threadIdx.x] = 0.f;
    __syncthreads();

    // per-lane: probability of target class; per-class prob kept for sum_p
    float pat = 0.f;
    float sump[NC];
#pragma unroll
    for (int c = 0; c < NC; ++c) {
        const float p = x[c] * iw;
        sump[c] = p;
        pat += (c == t) ? p : 0.f;                       // static reg index only
    }

    // nominator / count: single dynamic-index LDS atomic per lane (no butterfly)
    if (t != IGNORE_C) {
        atomicAdd(&lds[t], pat);
        atomicAdd(&lds[2 * NC + t], 1.0f);
    }

    // sum_p: 64-lane butterfly (17 values x 6 levels)
#pragma unroll
    for (int c = 0; c < NC; ++c) {
#pragma unroll
        for (int off = 32; off > 0; off >>= 1)
            sump[c] += __shfl_down(sump[c], (unsigned)off, 64);
    }
    if ((threadIdx.x & 63) == 0) {
#pragma unroll
        for (int c = 0; c < NC; ++c) atomicAdd(&lds[NC + c], sump[c]);
    }
    __syncthreads();

    // 51 global atomic streams, each to its own 64-B line
    if (threadIdx.x < 3 * NC)
        atomicAdd(&acc[threadIdx.x * SLOT], lds[threadIdx.x]);
}

// ---------------------------------------------------------------------------
// Kernel 2: O(C) scalar epilogue on one thread.
// ---------------------------------------------------------------------------
__device__ __forceinline__ float bce_ones(float x) {
    // F.binary_cross_entropy(x, ones) = min(-log(max(x,1e-38)), 100)
    return fminf(-logf(fmaxf(x, 1e-38f)), 100.0f);
}

__global__ void al_finalize(const float* __restrict__ acc,
                            const float* __restrict__ f1_list,
                            float* __restrict__ out) {
    if (threadIdx.x != 0 || blockIdx.x != 0) return;

    float nom[NC], sump[NC], cnt[NC];
    float n_mask = 0.f;
    for (int c = 0; c < NC; ++c) {
        nom[c]  = acc[c * SLOT];
        sump[c] = acc[(NC + c) * SLOT];
        cnt[c]  = acc[(2 * NC + c) * SLOT];
        n_mask += cnt[c];
    }

    float loss_list[NC], newf1[NC];
    float count = 0.f;
    for (int c = 0; c < NC; ++c) {
        const bool has = cnt[c] > 0.f;
        const float prec = (sump[c] > 0.f) ? nom[c] / sump[c] : 0.f;
        const float rec  = has ? nom[c] / cnt[c] : 0.f;
        const float negc = n_mask - cnt[c];
        const float spec_num = (n_mask - sump[c]) - (cnt[c] - nom[c]);
        const float spec = (negc > 0.f) ? spec_num / negc : 0.f;

        float ll = 0.f;
        if (has) {
            ll  = (sump[c] > 0.f) ? bce_ones(prec) : 0.f;
            ll += bce_ones(rec);
            ll += (negc > 0.f) ? bce_ones(spec) : 0.f;
        }
        loss_list[c] = ll;

        const float den = prec + rec;
        const float f1  = (den > 0.f) ? 2.f * prec * rec / den : 0.f;
        const float cur = has ? f1 : 0.f;
        newf1[c] = BETA_C * f1_list[c] + (1.f - BETA_C) * cur;
        count += has ? 1.f : 0.f;
    }

    const float wp = WPC_C * count;

    float mxl = -INFINITY;
    for (int c = 0; c < NC; ++c) {
        const float lg = (loss_list[c] != 0.f) ? ALPHA_C * (1.f - newf1[c]) : -INFINITY;
        mxl = fmaxf(mxl, lg);
    }
    float e[NC];
    float se = 0.f;
    for (int c = 0; c < NC; ++c) {
        const float lg = (loss_list[c] != 0.f) ? ALPHA_C * (1.f - newf1[c]) : -INFINITY;
        e[c] = expf(lg - mxl);    // exp(-inf) = 0 for unselected classes
        se += e[c];
    }

    float total = 0.f;
    for (int c = 0; c < NC; ++c) {
        const float sm = e[c] / se;
        total += loss_list[c] * (1.f + wp * sm);
    }
    out[0] = total / (count * (1.f + WPC_C));
}

// ---------------------------------------------------------------------------
extern "C" void kernel_launch(void* const* d_in, const int* in_sizes, int n_in,
                              void* d_out, int out_size, void* d_ws, size_t ws_size,
                              hipStream_t stream) {
    const float* pred    = (const float*)d_in[0];
    const int*   tgt     = (const int*)d_in[1];
    const float* f1_list = (const float*)d_in[2];
    float* out = (float*)d_out;
    float* acc = (float*)d_ws;

    hipMemsetAsync(acc, 0, 3 * NC * SLOT * sizeof(float), stream);
    al_reduce<<<dim3(NBLK), dim3(256), 0, stream>>>(pred, tgt, acc);
    al_finalize<<<dim3(1), dim3(64), 0, stream>>>(acc, f1_list, out);
}

// Round 5
// 57.165 us; speedup vs baseline: 2.6326x; 2.6326x over previous
//
#include <hip/hip_runtime.h>
#include <math.h>

#define NC 17
#define PLANE 640000              // 200*200*16 voxels per batch
#define H2 (PLANE / 2)            // 320000 float2 per channel-plane
#define BPB1 1250                 // blocks per batch in k1 (1250*256 = 320000)
#define NBLK1 (2 * BPB1)          // 2500 blocks
#define PCOLS 2504                // padded row length in part[] (floats)
#define BETA_C 0.95f
#define ALPHA_C 5.0f
#define WPC_C 3.0f
#define IGNORE_C 255

// ws layout: part[51][PCOLS] floats, then acc[51] floats.
// row r = kind*17 + c, kind: 0=nominator, 1=sum_p, 2=sum_comp(count)

// ---------------------------------------------------------------------------
// K1: softmax + per-class block partials. 2 voxels/thread (float2). No atomics
// to global memory: block writes 51 partials via plain scattered stores.
// ---------------------------------------------------------------------------
__global__ __launch_bounds__(256) void al_reduce1(const float* __restrict__ pred,
                                                  const int* __restrict__ tgt,
                                                  float* __restrict__ part) {
    const int bb = blockIdx.x;
    const int b  = (bb >= BPB1) ? 1 : 0;                     // block-uniform
    const int n2 = (bb - b * BPB1) * 256 + (int)threadIdx.x; // float2 index
    const float2* p0 = reinterpret_cast<const float2*>(pred)
                       + (size_t)(b * NC) * H2 + n2;
    const int2 t2 = reinterpret_cast<const int2*>(tgt)[b * H2 + n2];

    float2 x[NC];
#pragma unroll
    for (int c = 0; c < NC; ++c) x[c] = p0[(size_t)c * H2];
    __builtin_amdgcn_sched_barrier(0);   // keep all 17 loads issued up front

    float2 mx = x[0];
#pragma unroll
    for (int c = 1; c < NC; ++c) {
        mx.x = fmaxf(mx.x, x[c].x);
        mx.y = fmaxf(mx.y, x[c].y);
    }

    float2 s = make_float2(0.f, 0.f);
#pragma unroll
    for (int c = 0; c < NC; ++c) {
        x[c].x = __expf(x[c].x - mx.x); s.x += x[c].x;
        x[c].y = __expf(x[c].y - mx.y); s.y += x[c].y;
    }

    const float i0 = ((t2.x != IGNORE_C) ? 1.0f : 0.0f) / s.x;
    const float i1 = ((t2.y != IGNORE_C) ? 1.0f : 0.0f) / s.y;

    __shared__ float lds[3 * NC];
    if (threadIdx.x < 3 * NC) lds[threadIdx.x] = 0.f;
    __syncthreads();

    // per-class probabilities; target prob via static-index select
    float pat0 = 0.f, pat1 = 0.f;
    float sump[NC];
#pragma unroll
    for (int c = 0; c < NC; ++c) {
        const float px = x[c].x * i0;
        const float py = x[c].y * i1;
        sump[c] = px + py;
        pat0 += (c == t2.x) ? px : 0.f;
        pat1 += (c == t2.y) ? py : 0.f;
    }

    // nominator / count: dynamic-index LDS atomics (~4-way avg collision)
    if (t2.x != IGNORE_C) { atomicAdd(&lds[t2.x], pat0); atomicAdd(&lds[2 * NC + t2.x], 1.0f); }
    if (t2.y != IGNORE_C) { atomicAdd(&lds[t2.y], pat1); atomicAdd(&lds[2 * NC + t2.y], 1.0f); }

    // sum_p: 64-lane butterfly (17 x 6 shuffles)
#pragma unroll
    for (int c = 0; c < NC; ++c) {
#pragma unroll
        for (int off = 32; off > 0; off >>= 1)
            sump[c] += __shfl_down(sump[c], (unsigned)off, 64);
    }
    if ((threadIdx.x & 63) == 0) {
#pragma unroll
        for (int c = 0; c < NC; ++c) atomicAdd(&lds[NC + c], sump[c]);
    }
    __syncthreads();

    // transposed partial store: row r, column = blockIdx -> k2 reads contiguous
    if (threadIdx.x < 3 * NC)
        part[(size_t)threadIdx.x * PCOLS + bb] = lds[threadIdx.x];
}

// ---------------------------------------------------------------------------
// K2: one wave per accumulator row; coalesced row sum of 2500 partials.
// ---------------------------------------------------------------------------
__global__ __launch_bounds__(64) void al_reduce2(const float* __restrict__ part,
                                                 float* __restrict__ acc) {
    const int r = blockIdx.x;            // 0..50
    const int lane = (int)threadIdx.x;   // 0..63
    const float* p = part + (size_t)r * PCOLS;
    float s = 0.f;
    for (int i = lane; i < NBLK1; i += 64) s += p[i];
#pragma unroll
    for (int off = 32; off > 0; off >>= 1) s += __shfl_down(s, (unsigned)off, 64);
    if (lane == 0) acc[r] = s;
}

// ---------------------------------------------------------------------------
// K3: O(C) scalar epilogue.
// ---------------------------------------------------------------------------
__device__ __forceinline__ float bce_ones(float x) {
    // F.binary_cross_entropy(x, ones) = min(-log(max(x,1e-38)), 100)
    return fminf(-logf(fmaxf(x, 1e-38f)), 100.0f);
}

__global__ void al_finalize(const float* __restrict__ acc,
                            const float* __restrict__ f1_list,
                            float* __restrict__ out) {
    if (threadIdx.x != 0 || blockIdx.x != 0) return;

    float nom[NC], sump[NC], cnt[NC];
    float n_mask = 0.f;
    for (int c = 0; c < NC; ++c) {
        nom[c]  = acc[c];
        sump[c] = acc[NC + c];
        cnt[c]  = acc[2 * NC + c];
        n_mask += cnt[c];
    }

    float loss_list[NC], newf1[NC];
    float count = 0.f;
    for (int c = 0; c < NC; ++c) {
        const bool has = cnt[c] > 0.f;
        const float prec = (sump[c] > 0.f) ? nom[c] / sump[c] : 0.f;
        const float rec  = has ? nom[c] / cnt[c] : 0.f;
        const float negc = n_mask - cnt[c];
        const float spec_num = (n_mask - sump[c]) - (cnt[c] - nom[c]);
        const float spec = (negc > 0.f) ? spec_num / negc : 0.f;

        float ll = 0.f;
        if (has) {
            ll  = (sump[c] > 0.f) ? bce_ones(prec) : 0.f;
            ll += bce_ones(rec);
            ll += (negc > 0.f) ? bce_ones(spec) : 0.f;
        }
        loss_list[c] = ll;

        const float den = prec + rec;
        const float f1  = (den > 0.f) ? 2.f * prec * rec / den : 0.f;
        const float cur = has ? f1 : 0.f;
        newf1[c] = BETA_C * f1_list[c] + (1.f - BETA_C) * cur;
        count += has ? 1.f : 0.f;
    }

    const float wp = WPC_C * count;

    float mxl = -INFINITY;
    for (int c = 0; c < NC; ++c) {
        const float lg = (loss_list[c] != 0.f) ? ALPHA_C * (1.f - newf1[c]) : -INFINITY;
        mxl = fmaxf(mxl, lg);
    }
    float e[NC];
    float se = 0.f;
    for (int c = 0; c < NC; ++c) {
        const float lg = (loss_list[c] != 0.f) ? ALPHA_C * (1.f - newf1[c]) : -INFINITY;
        e[c] = expf(lg - mxl);    // exp(-inf) = 0 for unselected classes
        se += e[c];
    }

    float total = 0.f;
    for (int c = 0; c < NC; ++c) {
        const float sm = e[c] / se;
        total += loss_list[c] * (1.f + wp * sm);
    }
    out[0] = total / (count * (1.f + WPC_C));
}

// ---------------------------------------------------------------------------
extern "C" void kernel_launch(void* const* d_in, const int* in_sizes, int n_in,
                              void* d_out, int out_size, void* d_ws, size_t ws_size,
                              hipStream_t stream) {
    const float* pred    = (const float*)d_in[0];
    const int*   tgt     = (const int*)d_in[1];
    const float* f1_list = (const float*)d_in[2];
    float* out  = (float*)d_out;
    float* part = (float*)d_ws;                       // 51 * PCOLS floats
    float* acc  = part + (size_t)(3 * NC) * PCOLS;    // 51 floats

    al_reduce1<<<dim3(NBLK1), dim3(256), 0, stream>>>(pred, tgt, part);
    al_reduce2<<<dim3(3 * NC), dim3(64), 0, stream>>>(part, acc);
    al_finalize<<<dim3(1), dim3(64), 0, stream>>>(acc, f1_list, out);
}